// Round 1
// 743.939 us; speedup vs baseline: 1.0090x; 1.0090x over previous
//
#include <hip/hip_runtime.h>
#include <stdint.h>

// ---------- bf16 helpers (raw ushort storage) ----------
__device__ __forceinline__ float bf2f(unsigned short h) {
    union { unsigned int u; float f; } x;
    x.u = ((unsigned int)h) << 16;
    return x.f;
}
__device__ __forceinline__ unsigned short f2bf(float f) {
    union { float f; unsigned int u; } x;
    x.f = f;
    unsigned int u = x.u;
    unsigned int r = (u + 0x7FFFu + ((u >> 16) & 1u)) >> 16;  // RNE
    return (unsigned short)r;
}
// pack two fp32 -> bf16x2 (round-half-up; differs from RNE only at exact ties)
__device__ __forceinline__ unsigned pk2(float a, float b) {
    unsigned ua = __float_as_uint(a) + 0x8000u;
    unsigned ub = __float_as_uint(b) + 0x8000u;
    return __builtin_amdgcn_perm(ub, ua, 0x07060302);  // D = [ua.hi16 | ub.hi16]
}

typedef __attribute__((ext_vector_type(8))) short short8;
typedef __attribute__((ext_vector_type(4))) float floatx4;

// ---------------------------------------------------------------------------
// Streaming encode GEMM: C[:,set*64 .. +64) = lrelu(A[N,768](fp32) @ Bt^T + b)
// LDS-staged tile GEMM: BM=64, BN=64, BK=64, 256 threads (4 waves).
// A loaded per-lane-contiguous (float4) -> cvt bf16 -> swizzled LDS tile;
// B (bf16, L2-resident) reg-staged into swizzled LDS per k-step.
// 16 KB LDS/block -> 8 blocks/CU; grid ~1564 blocks for latency hiding.
// Chunk swizzle: 16B chunk index XOR (row&7) -> conflict-free ds_read_b128.
// ---------------------------------------------------------------------------
__global__ __launch_bounds__(256) void k_encode(
    const float* __restrict__ Ades, const float* __restrict__ Atw,
    const unsigned short* __restrict__ BtDes, const unsigned short* __restrict__ BtTw,
    const unsigned short* __restrict__ bias_bf,  // [bd 64][bt 64]
    unsigned short* __restrict__ C, int M)
{
    __shared__ __align__(16) unsigned short Asw[64 * 64];  // [row][k] bf16, swizzled, 8 KB
    __shared__ __align__(16) unsigned short Bsw[64 * 64];  // [col][k] bf16, swizzled, 8 KB

    const int set = blockIdx.y;
    const float* A = set ? Atw : Ades;
    const unsigned short* Bt = set ? BtTw : BtDes;
    const unsigned short* bias = bias_bf + set * 64;
    const int colofs = set * 64;
    const int tid  = threadIdx.x;
    const int wv   = tid >> 6, lane = tid & 63;
    const int quad = lane >> 4, l16 = lane & 15;
    const int m0   = blockIdx.x * 64;

    // staging coords
    const int ar  = tid >> 4;   // row within 16-row pass (A)
    const int af4 = tid & 15;   // float4 index within row (16 x 16B = 64 floats)
    const int bcol = tid >> 3;  // col within 32-col pass (B)
    const int bq   = tid & 7;   // source 16B chunk (8 x 16B = 64 bf16)

    floatx4 acc[4];
#pragma unroll
    for (int j = 0; j < 4; j++) acc[j] = (floatx4){0.f, 0.f, 0.f, 0.f};

    for (int kt = 0; kt < 768; kt += 64) {
        if (kt) __syncthreads();
        // ---- stage A: 64 rows x 64 k (fp32 -> bf16), coalesced float4 loads ----
#pragma unroll
        for (int p = 0; p < 4; p++) {
            int row = p * 16 + ar;
            int gr = m0 + row; if (gr > M - 1) gr = M - 1;
            float4 v = *(const float4*)(A + (size_t)gr * 768 + kt + af4 * 4);
            unsigned w0 = pk2(v.x, v.y), w1 = pk2(v.z, v.w);
            int qd = (af4 >> 1) ^ (row & 7);     // swizzled 16B-chunk index
            uint2 u; u.x = w0; u.y = w1;
            *(uint2*)&Asw[row * 64 + qd * 8 + (af4 & 1) * 4] = u;
        }
        // ---- stage B: 64 cols x 64 k (bf16, from L2), coalesced 16B loads ----
#pragma unroll
        for (int p = 0; p < 2; p++) {
            int col = p * 32 + bcol;
            short8 bv = *(const short8*)(Bt + (size_t)col * 768 + kt + bq * 8);
            int qd = bq ^ (col & 7);
            *(short8*)&Bsw[col * 64 + qd * 8] = bv;
        }
        __syncthreads();
        // ---- compute: 2 k-subtiles x 4 n-tiles ----
#pragma unroll
        for (int s = 0; s < 2; s++) {
            int arow = wv * 16 + l16;
            int ca = (s * 4 + quad) ^ (arow & 7);
            short8 av = *(const short8*)&Asw[arow * 64 + ca * 8];
#pragma unroll
            for (int j = 0; j < 4; j++) {
                int bcl = j * 16 + l16;
                int cb = (s * 4 + quad) ^ (bcl & 7);
                short8 bvr = *(const short8*)&Bsw[bcl * 64 + cb * 8];
                acc[j] = __builtin_amdgcn_mfma_f32_16x16x32_bf16(av, bvr, acc[j], 0, 0, 0);
            }
        }
    }

    // epilogue: C/D layout col = lane&15 (within n-tile), row = quad*4 + reg
#pragma unroll
    for (int j = 0; j < 4; j++) {
        float bv = bf2f(bias[j * 16 + l16]);
#pragma unroll
        for (int r = 0; r < 4; r++) {
            int gr = m0 + wv * 16 + quad * 4 + r;
            if (gr < M) {
                float v = acc[j][r] + bv;
                v = v > 0.f ? v : 0.01f * v;
                C[(size_t)gr * 256 + colofs + j * 16 + l16] = f2bf(v);
            }
        }
    }
}

// ---------------------------------------------------------------------------
// Tiled MFMA GEMM (bf16 A in up to three 256-col parts).
// BM=128, BK=64, 256 threads = 4 waves, BN=128 -> 4x4 MFMA per wave.
// ---------------------------------------------------------------------------
__global__ __launch_bounds__(256) void gemm_nt(
    const unsigned short* __restrict__ A0, const unsigned short* __restrict__ A1,
    const unsigned short* __restrict__ A2, int lda,
    const unsigned short* __restrict__ Bt, int ldb,
    unsigned short* __restrict__ C, int ldc,
    const unsigned short* __restrict__ bias,
    int M, int K, int act)
{
    constexpr int BM = 128, BN = 128, BK = 64;
    const int tid  = threadIdx.x;
    const int wave = tid >> 6;
    const int lane = tid & 63;
    const int quad = lane >> 4;
    const int l16  = lane & 15;
    const int m0   = blockIdx.x * BM;
    const int n0   = blockIdx.y * BN;
    const int wm   = (wave & 1) * 64;
    const int wn   = (wave >> 1) * 64;

    __shared__ short8 As[8 * (BM + 2)];
    __shared__ short8 Bs[8 * (BN + 2)];

    floatx4 acc[4][4];
#pragma unroll
    for (int i = 0; i < 4; i++)
#pragma unroll
        for (int j = 0; j < 4; j++) acc[i][j] = (floatx4){0.f, 0.f, 0.f, 0.f};

    for (int kt = 0; kt < K; kt += BK) {
        const unsigned short* Ap = (kt < 256) ? A0 : (kt < 512) ? A1 : A2;
        const int ko = kt & 255;
#pragma unroll
        for (int c = 0; c < 4; c++) {
            int lin = c * 256 + tid;
            int row = lin >> 3, kq = lin & 7;
            int gr = m0 + row; if (gr > M - 1) gr = M - 1;
            As[kq * (BM + 2) + row] = *(const short8*)(Ap + (size_t)gr * lda + ko + kq * 8);
        }
#pragma unroll
        for (int c = 0; c < 4; c++) {
            int lin = c * 256 + tid;
            int n = lin >> 3, kq = lin & 7;
            Bs[kq * (BN + 2) + n] = *(const short8*)(Bt + (size_t)(n0 + n) * ldb + kt + kq * 8);
        }
        __syncthreads();
#pragma unroll
        for (int s = 0; s < 2; s++) {
            short8 af[4], bfr[4];
#pragma unroll
            for (int i = 0; i < 4; i++)
                af[i] = As[(s * 4 + quad) * (BM + 2) + wm + i * 16 + l16];
#pragma unroll
            for (int j = 0; j < 4; j++)
                bfr[j] = Bs[(s * 4 + quad) * (BN + 2) + wn + j * 16 + l16];
#pragma unroll
            for (int i = 0; i < 4; i++)
#pragma unroll
                for (int j = 0; j < 4; j++)
                    acc[i][j] = __builtin_amdgcn_mfma_f32_16x16x32_bf16(
                        af[i], bfr[j], acc[i][j], 0, 0, 0);
        }
        __syncthreads();
    }

#pragma unroll
    for (int j = 0; j < 4; j++) {
        int gc = n0 + wn + j * 16 + l16;
        float bv = bias ? bf2f(bias[gc]) : 0.f;
#pragma unroll
        for (int i = 0; i < 4; i++) {
            int grb = m0 + wm + i * 16 + quad * 4;
#pragma unroll
            for (int r = 0; r < 4; r++) {
                int gr = grb + r;
                if (gr < M) {
                    float v = acc[i][j][r] + bv;
                    if (act) v = v > 0.f ? v : 0.01f * v;
                    C[(size_t)gr * ldc + gc] = f2bf(v);
                }
            }
        }
    }
}

// ---------- fused weight prep (all fp32 -> bf16) ----------
__global__ void k_prep(const float* __restrict__ Wd, const float* __restrict__ Wt,
                       const float* __restrict__ Wi, const float* __restrict__ Wo1,
                       const float* __restrict__ root1, const float* __restrict__ rel1,
                       const float* __restrict__ root2, const float* __restrict__ rel2,
                       const float* __restrict__ bd, const float* __restrict__ bt,
                       const float* __restrict__ bi, const float* __restrict__ b1,
                       const float* __restrict__ b2, const float* __restrict__ bo1,
                       unsigned short* __restrict__ WdT, unsigned short* __restrict__ WtT,
                       unsigned short* __restrict__ WiT, unsigned short* __restrict__ Wo1T,
                       unsigned short* __restrict__ BT1, unsigned short* __restrict__ BT2,
                       unsigned short* __restrict__ bias_bf)
{
    int i = blockIdx.x * 256 + threadIdx.x;
    if (i < 49152) { int r = i >> 6, c = i & 63; WdT[c * 768 + r] = f2bf(Wd[i]); return; }
    i -= 49152;
    if (i < 49152) { int r = i >> 6, c = i & 63; WtT[c * 768 + r] = f2bf(Wt[i]); return; }
    i -= 49152;
    if (i < 65536) { int r = i >> 8, c = i & 255; WiT[c * 256 + r] = f2bf(Wi[i]); return; }
    i -= 65536;
    if (i < 65536) { int r = i >> 8, c = i & 255; Wo1T[c * 256 + r] = f2bf(Wo1[i]); return; }
    i -= 65536;
    if (i < 196608) {
        int k = i % 768, n = i / 768;
        BT1[i] = f2bf(k < 256 ? root1[k * 256 + n] : rel1[(k - 256) * 256 + n]);
        return;
    }
    i -= 196608;
    if (i < 196608) {
        int k = i % 768, n = i / 768;
        BT2[i] = f2bf(k < 256 ? root2[k * 256 + n] : rel2[(k - 256) * 256 + n]);
        return;
    }
    i -= 196608;
    if (i < 1152) {
        const float* p; int off;
        if (i < 64)       { p = bd;  off = i; }
        else if (i < 128) { p = bt;  off = i - 64; }
        else if (i < 384) { p = bi;  off = i - 128; }
        else if (i < 640) { p = b1;  off = i - 384; }
        else if (i < 896) { p = b2;  off = i - 640; }
        else              { p = bo1; off = i - 896; }
        bias_bf[i] = f2bf(p[off]);
    }
}

// ---------- CSR build ----------
__global__ void k_hist(const int* __restrict__ ei, const int* __restrict__ et,
                       int* cnt2, int N, int E) {
    int e = blockIdx.x * 256 + threadIdx.x;
    if (e < E) {
        int dst = ei[E + e];
        int t = et[e] & 1;
        if ((unsigned)dst < (unsigned)N) atomicAdd(&cnt2[t * N + dst], 1);
    }
}

__global__ void k_scan1(const int* __restrict__ cnt2, int* rowptr, int* bsum, int N) {
    __shared__ int sh[256];
    int t = threadIdx.x;
    int base = blockIdx.x * 1024 + t * 4;
    int v[4];
    int s = 0;
#pragma unroll
    for (int k = 0; k < 4; k++) {
        int idx = base + k;
        v[k] = (idx < N) ? (cnt2[idx] + cnt2[N + idx]) : 0;
        s += v[k];
    }
    sh[t] = s;
    __syncthreads();
    for (int off = 1; off < 256; off <<= 1) {
        int x = 0;
        if (t >= off) x = sh[t - off];
        __syncthreads();
        if (t >= off) sh[t] += x;
        __syncthreads();
    }
    int excl = sh[t] - s;
    int run = excl;
#pragma unroll
    for (int k = 0; k < 4; k++) {
        int idx = base + k;
        if (idx < N) rowptr[idx] = run;
        run += v[k];
    }
    if (t == 255) bsum[blockIdx.x] = sh[255];
}

__global__ void k_scan2(const int* __restrict__ bsum, int* bofs, int nb) {
    int t = threadIdx.x;  // 64
    int v = (t < nb) ? bsum[t] : 0;
    int orig = v;
    for (int off = 1; off < 64; off <<= 1) {
        int x = __shfl_up(v, off);
        if (t >= off) v += x;
    }
    if (t < nb) bofs[t] = v - orig;
}

__global__ void k_scan3(int* rowptr, const int* __restrict__ bofs, int N) {
    int i = blockIdx.x * 256 + threadIdx.x;
    if (i < N) rowptr[i] += bofs[i >> 10];
}

__global__ void k_fill(const int* __restrict__ ei, const int* __restrict__ et,
                       const int* __restrict__ rowptr, int* cursor, int* sorted,
                       int N, int E) {
    int e = blockIdx.x * 256 + threadIdx.x;
    if (e < E) {
        int src = ei[e];
        int dst = ei[E + e];
        int t = et[e] & 1;
        if ((unsigned)dst < (unsigned)N && (unsigned)src < (unsigned)N) {
            int pos = rowptr[dst] + atomicAdd(&cursor[dst], 1);
            sorted[pos] = src | (t << 24);
        }
    }
}

// ---------- aggregation: one wave per node, 2 edges/iter, 4 loads in flight ----------
__global__ __launch_bounds__(256) void k_agg(
    const unsigned short* __restrict__ x,
    unsigned short* __restrict__ m0,
    unsigned short* __restrict__ m1,
    int N,
    const int* __restrict__ rowptr, const int* __restrict__ cnt2,
    const int* __restrict__ sorted)
{
    int wave = threadIdx.x >> 6;
    int lane = threadIdx.x & 63;
    int half = lane >> 5;
    int l32  = lane & 31;
    int node = blockIdx.x * 4 + wave;
    if (node >= N) return;

    int start = rowptr[node];
    int c0 = cnt2[node], c1 = cnt2[N + node];
    int deg = c0 + c1;

    float a0[8] = {0,0,0,0,0,0,0,0};
    float a1[8] = {0,0,0,0,0,0,0,0};

    for (int b = 0; b < deg; b += 64) {
        int rem = deg - b; if (rem > 64) rem = 64;
        int p = 0;
        if (lane < rem) p = sorted[start + b + lane];
        int iters = (rem + 1) >> 1;
        for (int t = 0; t < iters; t += 2) {
            int e0 = 2 * t + half;
            int e1 = e0 + 2;
            int q0 = __shfl(p, e0 < 64 ? e0 : 63);
            int q1 = __shfl(p, e1 < 64 ? e1 : 63);
            bool v0ok = e0 < rem;
            bool v1ok = e1 < rem;
            int s0 = q0 & 0xFFFFFF; if (s0 >= N) s0 = 0;
            int s1 = q1 & 0xFFFFFF; if (s1 >= N) s1 = 0;
            uint4 r0 = *((const uint4*)(x + (size_t)s0 * 256) + l32);
            uint4 r1 = *((const uint4*)(x + (size_t)s1 * 256) + l32);
            if (v0ok) {
                float f[8];
                f[0] = bf2f((unsigned short)(r0.x & 0xFFFFu)); f[1] = bf2f((unsigned short)(r0.x >> 16));
                f[2] = bf2f((unsigned short)(r0.y & 0xFFFFu)); f[3] = bf2f((unsigned short)(r0.y >> 16));
                f[4] = bf2f((unsigned short)(r0.z & 0xFFFFu)); f[5] = bf2f((unsigned short)(r0.z >> 16));
                f[6] = bf2f((unsigned short)(r0.w & 0xFFFFu)); f[7] = bf2f((unsigned short)(r0.w >> 16));
                if ((q0 >> 24) & 1) {
#pragma unroll
                    for (int k = 0; k < 8; k++) a1[k] += f[k];
                } else {
#pragma unroll
                    for (int k = 0; k < 8; k++) a0[k] += f[k];
                }
            }
            if (v1ok) {
                float f[8];
                f[0] = bf2f((unsigned short)(r1.x & 0xFFFFu)); f[1] = bf2f((unsigned short)(r1.x >> 16));
                f[2] = bf2f((unsigned short)(r1.y & 0xFFFFu)); f[3] = bf2f((unsigned short)(r1.y >> 16));
                f[4] = bf2f((unsigned short)(r1.z & 0xFFFFu)); f[5] = bf2f((unsigned short)(r1.z >> 16));
                f[6] = bf2f((unsigned short)(r1.w & 0xFFFFu)); f[7] = bf2f((unsigned short)(r1.w >> 16));
                if ((q1 >> 24) & 1) {
#pragma unroll
                    for (int k = 0; k < 8; k++) a1[k] += f[k];
                } else {
#pragma unroll
                    for (int k = 0; k < 8; k++) a0[k] += f[k];
                }
            }
        }
    }
#pragma unroll
    for (int k = 0; k < 8; k++) {
        a0[k] += __shfl_xor(a0[k], 32);
        a1[k] += __shfl_xor(a1[k], 32);
    }
    float i0 = c0 > 0 ? 1.f / (float)c0 : 0.f;
    float i1 = c1 > 0 ? 1.f / (float)c1 : 0.f;
    uint4 o;
    if (half == 0) {
        o.x = (unsigned)f2bf(a0[0] * i0) | ((unsigned)f2bf(a0[1] * i0) << 16);
        o.y = (unsigned)f2bf(a0[2] * i0) | ((unsigned)f2bf(a0[3] * i0) << 16);
        o.z = (unsigned)f2bf(a0[4] * i0) | ((unsigned)f2bf(a0[5] * i0) << 16);
        o.w = (unsigned)f2bf(a0[6] * i0) | ((unsigned)f2bf(a0[7] * i0) << 16);
        *((uint4*)(m0 + (size_t)node * 256) + l32) = o;
    } else {
        o.x = (unsigned)f2bf(a1[0] * i1) | ((unsigned)f2bf(a1[1] * i1) << 16);
        o.y = (unsigned)f2bf(a1[2] * i1) | ((unsigned)f2bf(a1[3] * i1) << 16);
        o.z = (unsigned)f2bf(a1[4] * i1) | ((unsigned)f2bf(a1[5] * i1) << 16);
        o.w = (unsigned)f2bf(a1[6] * i1) | ((unsigned)f2bf(a1[7] * i1) << 16);
        *((uint4*)(m1 + (size_t)node * 256) + l32) = o;
    }
}

// ---------- small-K encode (num K=5 -> cols 128..191, cat K=3 -> 192..255) ----------
__global__ void k_small(const float* __restrict__ num, const float* __restrict__ cat,
                        const float* __restrict__ Wn, const float* __restrict__ bnp,
                        const float* __restrict__ Wc, const float* __restrict__ bcp,
                        unsigned short* __restrict__ xcat, int N)
{
    __shared__ float wn[320], wc[192], bns[64], bcs[64];
    int t = threadIdx.x;
    for (int i = t; i < 320; i += 256) wn[i] = Wn[i];
    for (int i = t; i < 192; i += 256) wc[i] = Wc[i];
    if (t < 64) { bns[t] = bnp[t]; bcs[t] = bcp[t]; }
    __syncthreads();

    int node = blockIdx.x * 128 + (t >> 1);
    int half = t & 1;
    if (node >= N) return;
    if (half == 0) {
        float in5[5];
#pragma unroll
        for (int i = 0; i < 5; i++) in5[i] = num[(size_t)node * 5 + i];
        unsigned short* orow = xcat + (size_t)node * 256 + 128;
#pragma unroll 4
        for (int c = 0; c < 64; c++) {
            float v = bns[c];
#pragma unroll
            for (int i = 0; i < 5; i++) v += in5[i] * wn[i * 64 + c];
            v = v > 0.f ? v : 0.01f * v;
            orow[c] = f2bf(v);
        }
    } else {
        float in3[3];
#pragma unroll
        for (int i = 0; i < 3; i++) in3[i] = cat[(size_t)node * 3 + i];
        unsigned short* orow = xcat + (size_t)node * 256 + 192;
#pragma unroll 4
        for (int c = 0; c < 64; c++) {
            float v = bcs[c];
#pragma unroll
            for (int i = 0; i < 3; i++) v += in3[i] * wc[i * 64 + c];
            v = v > 0.f ? v : 0.01f * v;
            orow[c] = f2bf(v);
        }
    }
}

// ---------- final projection: out[N,2](fp32) = z[N,256] @ Wo2[256,2] + bo2 ----------
__global__ __launch_bounds__(256) void k_final(
    const unsigned short* __restrict__ z,
    const float* __restrict__ Wo2, const float* __restrict__ bo2,
    float* __restrict__ out, int N)
{
    __shared__ float w[512];
    int t = threadIdx.x;
    for (int i = t; i < 512; i += 256) w[i] = Wo2[i];
    __syncthreads();
    int wave = t >> 6, lane = t & 63;
    int node = blockIdx.x * 4 + wave;
    if (node >= N) return;
    uint2 raw = *((const uint2*)(z + (size_t)node * 256) + lane);
    float v0 = bf2f((unsigned short)(raw.x & 0xFFFFu));
    float v1 = bf2f((unsigned short)(raw.x >> 16));
    float v2 = bf2f((unsigned short)(raw.y & 0xFFFFu));
    float v3 = bf2f((unsigned short)(raw.y >> 16));
    int k0 = lane * 4;
    float s0 = v0 * w[k0 * 2]     + v1 * w[(k0 + 1) * 2]     + v2 * w[(k0 + 2) * 2]     + v3 * w[(k0 + 3) * 2];
    float s1 = v0 * w[k0 * 2 + 1] + v1 * w[(k0 + 1) * 2 + 1] + v2 * w[(k0 + 2) * 2 + 1] + v3 * w[(k0 + 3) * 2 + 1];
    for (int off = 32; off; off >>= 1) {
        s0 += __shfl_xor(s0, off);
        s1 += __shfl_xor(s1, off);
    }
    if (lane == 0) {
        out[(size_t)node * 2]     = s0 + bo2[0];
        out[(size_t)node * 2 + 1] = s1 + bo2[1];
    }
}

// ---------------------------------------------------------------------------
extern "C" void kernel_launch(void* const* d_in, const int* in_sizes, int n_in,
                              void* d_out, int out_size, void* d_ws, size_t ws_size,
                              hipStream_t stream)
{
    (void)n_in; (void)out_size; (void)ws_size;
    const float* des   = (const float*)d_in[0];
    const float* tweet = (const float*)d_in[1];
    const float* nump  = (const float*)d_in[2];
    const float* catp  = (const float*)d_in[3];
    const int*   ei    = (const int*)d_in[4];
    const int*   et    = (const int*)d_in[5];
    const float* Wd  = (const float*)d_in[6];
    const float* bd  = (const float*)d_in[7];
    const float* Wt  = (const float*)d_in[8];
    const float* bt  = (const float*)d_in[9];
    const float* Wn  = (const float*)d_in[10];
    const float* bn  = (const float*)d_in[11];
    const float* Wc  = (const float*)d_in[12];
    const float* bc  = (const float*)d_in[13];
    const float* Wi  = (const float*)d_in[14];
    const float* bi  = (const float*)d_in[15];
    const float* rel1  = (const float*)d_in[16];
    const float* root1 = (const float*)d_in[17];
    const float* bias1 = (const float*)d_in[18];
    const float* rel2  = (const float*)d_in[19];
    const float* root2 = (const float*)d_in[20];
    const float* bias2 = (const float*)d_in[21];
    const float* Wo1 = (const float*)d_in[22];
    const float* bo1 = (const float*)d_in[23];
    const float* Wo2 = (const float*)d_in[24];
    const float* bo2 = (const float*)d_in[25];

    const int N = in_sizes[0] / 768;
    const int E = in_sizes[5];

    char* ws = (char*)d_ws;
    size_t off = 0;
    auto alloc = [&](size_t bytes) -> char* {
        char* p = ws + off;
        off += (bytes + 255) & ~(size_t)255;
        return p;
    };
    unsigned short* B0 = (unsigned short*)alloc((size_t)N * 256 * 2);  // xcat / y1 / z
    unsigned short* B1 = (unsigned short*)alloc((size_t)N * 256 * 2);  // x / y2
    unsigned short* B2 = (unsigned short*)alloc((size_t)N * 256 * 2);  // m0
    unsigned short* B3 = (unsigned short*)alloc((size_t)N * 256 * 2);  // m1
    unsigned short* WdT  = (unsigned short*)alloc(64 * 768 * 2);
    unsigned short* WtT  = (unsigned short*)alloc(64 * 768 * 2);
    unsigned short* WiT  = (unsigned short*)alloc(256 * 256 * 2);
    unsigned short* Wo1T = (unsigned short*)alloc(256 * 256 * 2);
    unsigned short* BT1  = (unsigned short*)alloc(256 * 768 * 2);
    unsigned short* BT2  = (unsigned short*)alloc(256 * 768 * 2);
    unsigned short* bias_bf = (unsigned short*)alloc(1152 * 2);
    unsigned short* bd_bf = bias_bf;          // 64
    unsigned short* bi_bf = bias_bf + 128;    // 256
    unsigned short* b1_bf = bias_bf + 384;    // 256
    unsigned short* b2_bf = bias_bf + 640;    // 256
    unsigned short* bo1_bf = bias_bf + 896;   // 256
    int* cnt2   = (int*)alloc((size_t)2 * N * 4);   // adjacent to cursor
    int* cursor = (int*)alloc((size_t)N * 4);
    int* rowptr = (int*)alloc((size_t)(N + 1) * 4);
    int* bsum   = (int*)alloc(64 * 4);
    int* bofs   = (int*)alloc(64 * 4);
    int* sorted = (int*)alloc((size_t)E * 4);

    // zero cnt2 + cursor
    size_t zlen = (size_t)(((char*)cursor + (size_t)N * 4) - (char*)cnt2);
    hipMemsetAsync(cnt2, 0, zlen, stream);

    // fused weight prep: 623744 elements
    k_prep<<<(623744 + 255) / 256, 256, 0, stream>>>(
        Wd, Wt, Wi, Wo1, root1, rel1, root2, rel2,
        bd, bt, bi, bias1, bias2, bo1,
        WdT, WtT, WiT, Wo1T, BT1, BT2, bias_bf);

    // CSR build
    int eb = (E + 255) / 256;
    k_hist<<<eb, 256, 0, stream>>>(ei, et, cnt2, N, E);
    int nb = (N + 1023) / 1024;
    k_scan1<<<nb, 256, 0, stream>>>(cnt2, rowptr, bsum, N);
    k_scan2<<<1, 64, 0, stream>>>(bsum, bofs, nb);
    k_scan3<<<(N + 255) / 256, 256, 0, stream>>>(rowptr, bofs, N);
    k_fill<<<eb, 256, 0, stream>>>(ei, et, rowptr, cursor, sorted, N, E);

    // streaming feature encode -> B0 cols 0..127 (des 0..63, tweet 64..127)
    dim3 gEnc((N + 63) / 64, 2);
    k_encode<<<gEnc, 256, 0, stream>>>(des, tweet, WdT, WtT, bd_bf, B0, N);
    k_small<<<(N + 127) / 128, 256, 0, stream>>>(nump, catp, Wn, bn, Wc, bc, B0, N);

    // x = lrelu(xcat @ Wi + bi) -> B1
    dim3 g128((N + 127) / 128, 2);
    gemm_nt<<<g128, 256, 0, stream>>>(B0, B0, B0, 256, WiT, 256, B1, 256, bi_bf, N, 256, 1);

    // RGCN layer 1: aggregate x (B1) -> B2, B3; fused K=768 GEMM -> B0
    int ab = (N + 3) / 4;
    k_agg<<<ab, 256, 0, stream>>>(B1, B2, B3, N, rowptr, cnt2, sorted);
    gemm_nt<<<g128, 256, 0, stream>>>(B1, B2, B3, 256, BT1, 768, B0, 256, b1_bf, N, 768, 0);

    // RGCN layer 2: aggregate y1 (B0) -> B2, B3; GEMM -> B1
    k_agg<<<ab, 256, 0, stream>>>(B0, B2, B3, N, rowptr, cnt2, sorted);
    gemm_nt<<<g128, 256, 0, stream>>>(B0, B2, B3, 256, BT2, 768, B1, 256, b2_bf, N, 768, 0);

    // z = lrelu(y2 @ Wo1 + bo1) -> B0
    gemm_nt<<<g128, 256, 0, stream>>>(B1, B1, B1, 256, Wo1T, 256, B0, 256, bo1_bf, N, 256, 1);

    // out = z @ Wo2 + bo2 (fp32)
    k_final<<<ab, 256, 0, stream>>>(B0, Wo2, bo2, (float*)d_out, N);
}

// Round 2
// 741.929 us; speedup vs baseline: 1.0117x; 1.0027x over previous
//
#include <hip/hip_runtime.h>
#include <stdint.h>

// ---------- bf16 helpers (raw ushort storage) ----------
__device__ __forceinline__ float bf2f(unsigned short h) {
    union { unsigned int u; float f; } x;
    x.u = ((unsigned int)h) << 16;
    return x.f;
}
__device__ __forceinline__ unsigned short f2bf(float f) {
    union { float f; unsigned int u; } x;
    x.f = f;
    unsigned int u = x.u;
    unsigned int r = (u + 0x7FFFu + ((u >> 16) & 1u)) >> 16;  // RNE
    return (unsigned short)r;
}
// pack two fp32 -> bf16x2 (round-half-up; differs from RNE only at exact ties)
__device__ __forceinline__ unsigned pk2(float a, float b) {
    unsigned ua = __float_as_uint(a) + 0x8000u;
    unsigned ub = __float_as_uint(b) + 0x8000u;
    return __builtin_amdgcn_perm(ub, ua, 0x07060302);  // D = [ua.hi16 | ub.hi16]
}

// LDS-visibility barrier that does NOT drain vmcnt: in-flight global loads
// survive across it (unlike __syncthreads, which emits s_waitcnt vmcnt(0)).
__device__ __forceinline__ void pipe_barrier() {
    asm volatile("s_waitcnt lgkmcnt(0)" ::: "memory");
    __builtin_amdgcn_s_barrier();
}

typedef __attribute__((ext_vector_type(8))) short short8;
typedef __attribute__((ext_vector_type(4))) float floatx4;

// ---------------------------------------------------------------------------
// Streaming encode GEMM: C[:,set*64 .. +64) = lrelu(A[N,768](fp32) @ Bt^T + b)
// 2-phase pipelined tile GEMM: BM=64, BN=64, BK=64, 256 threads (4 waves).
// Reg-staged prefetch depth 2 (tile t+2 issued at iter t), LDS double-buffer,
// raw s_barrier + lgkmcnt(0) so global loads stay in flight across barriers;
// vmcnt is consumed counted (6), never drained to 0 in the main loop.
// Chunk swizzle: 16B chunk index XOR (row&7) -> conflict-free ds_read_b128.
// ---------------------------------------------------------------------------
__global__ __launch_bounds__(256) void k_encode(
    const float* __restrict__ Ades, const float* __restrict__ Atw,
    const unsigned short* __restrict__ BtDes, const unsigned short* __restrict__ BtTw,
    const unsigned short* __restrict__ bias_bf,  // [bd 64][bt 64]
    unsigned short* __restrict__ C, int M)
{
    __shared__ __align__(16) unsigned short Asw[2][64 * 64];  // 2 x 8 KB bf16
    __shared__ __align__(16) unsigned short Bsw[2][64 * 64];  // 2 x 8 KB bf16

    const int set = blockIdx.y;
    const float* A = set ? Atw : Ades;
    const unsigned short* Bt = set ? BtTw : BtDes;
    const unsigned short* bias = bias_bf + set * 64;
    const int colofs = set * 64;
    const int tid  = threadIdx.x;
    const int wv   = tid >> 6, lane = tid & 63;
    const int quad = lane >> 4, l16 = lane & 15;
    const int m0   = blockIdx.x * 64;

    // staging coords
    const int ar  = tid >> 4;   // A row within 16-row pass
    const int af4 = tid & 15;   // float4 index within row
    const int bcol = tid >> 3;  // B col within 32-col pass
    const int bq   = tid & 7;   // B 16B chunk
    const int awofs = ar * 64 + ((af4 >> 1) ^ (ar & 7)) * 8 + (af4 & 1) * 4;
    const int bwofs = bcol * 64 + (bq ^ (bcol & 7)) * 8;

    const float* ap[4];
#pragma unroll
    for (int p = 0; p < 4; p++) {
        int gr = m0 + p * 16 + ar; if (gr > M - 1) gr = M - 1;
        ap[p] = A + (size_t)gr * 768 + af4 * 4;
    }
    const unsigned short* bp0 = Bt + (size_t)bcol * 768 + bq * 8;
    const unsigned short* bp1 = bp0 + 32 * 768;

    float4 ra0[4], ra1[4];     // staged A regs, 2 tiles in flight
    short8 rb0[2], rb1[2];     // staged B regs

    floatx4 acc[4];
#pragma unroll
    for (int j = 0; j < 4; j++) acc[j] = (floatx4){0.f, 0.f, 0.f, 0.f};

    const int arow  = wv * 16 + l16;
    const int abase = arow * 64;
    const int amask = arow & 7;
    const int bmask = l16 & 7;

#define LOADT(t, RA, RB) { \
    _Pragma("unroll") for (int p = 0; p < 4; p++) RA[p] = *(const float4*)(ap[p] + (t) * 64); \
    RB[0] = *(const short8*)(bp0 + (t) * 64); \
    RB[1] = *(const short8*)(bp1 + (t) * 64); }

#define WRITET(buf, RA, RB) { \
    _Pragma("unroll") for (int p = 0; p < 4; p++) { \
        uint2 u; u.x = pk2(RA[p].x, RA[p].y); u.y = pk2(RA[p].z, RA[p].w); \
        *(uint2*)&Asw[buf][awofs + p * 1024] = u; } \
    *(short8*)&Bsw[buf][bwofs] = RB[0]; \
    *(short8*)&Bsw[buf][bwofs + 2048] = RB[1]; }

#define COMPUTET(buf) { \
    _Pragma("unroll") for (int s = 0; s < 2; s++) { \
        short8 av = *(const short8*)&Asw[buf][abase + ((s * 4 + quad) ^ amask) * 8]; \
        _Pragma("unroll") for (int j = 0; j < 4; j++) { \
            short8 bv = *(const short8*)&Bsw[buf][(j * 16 + l16) * 64 + ((s * 4 + quad) ^ bmask) * 8]; \
            acc[j] = __builtin_amdgcn_mfma_f32_16x16x32_bf16(av, bv, acc[j], 0, 0, 0); } } }

    // prologue: tiles 0,1 in flight; tile 0 -> LDS buf0
    LOADT(0, ra0, rb0);
    LOADT(1, ra1, rb1);
    WRITET(0, ra0, rb0);      // compiler emits counted vmcnt(6) here
    pipe_barrier();

    // 12 k-tiles, fully unrolled, 2 half-iters per tt (static buffer indices)
#pragma unroll
    for (int tt = 0; tt < 6; tt++) {
        const int t = tt * 2;
        if (t + 2 < 12) LOADT(t + 2, ra0, rb0);   // issue t+2 (stays in flight across barrier)
        COMPUTET(0);                              // tile t
        WRITET(1, ra1, rb1);                      // tile t+1 (vmcnt(6) wait, after compute)
        pipe_barrier();
        if (t + 3 < 12) LOADT(t + 3, ra1, rb1);
        COMPUTET(1);                              // tile t+1
        if (t + 2 < 12) WRITET(0, ra0, rb0);      // tile t+2
        pipe_barrier();
    }
#undef LOADT
#undef WRITET
#undef COMPUTET

    // epilogue: C/D layout col = lane&15 (within n-tile), row = quad*4 + reg
#pragma unroll
    for (int j = 0; j < 4; j++) {
        float bv = bf2f(bias[j * 16 + l16]);
#pragma unroll
        for (int r = 0; r < 4; r++) {
            int gr = m0 + wv * 16 + quad * 4 + r;
            if (gr < M) {
                float v = acc[j][r] + bv;
                v = v > 0.f ? v : 0.01f * v;
                C[(size_t)gr * 256 + colofs + j * 16 + l16] = f2bf(v);
            }
        }
    }
}

// ---------------------------------------------------------------------------
// Tiled MFMA GEMM (bf16 A in up to three 256-col parts).
// BM=128, BK=64, 256 threads = 4 waves, BN=128 -> 4x4 MFMA per wave.
// ---------------------------------------------------------------------------
__global__ __launch_bounds__(256) void gemm_nt(
    const unsigned short* __restrict__ A0, const unsigned short* __restrict__ A1,
    const unsigned short* __restrict__ A2, int lda,
    const unsigned short* __restrict__ Bt, int ldb,
    unsigned short* __restrict__ C, int ldc,
    const unsigned short* __restrict__ bias,
    int M, int K, int act)
{
    constexpr int BM = 128, BN = 128, BK = 64;
    const int tid  = threadIdx.x;
    const int wave = tid >> 6;
    const int lane = tid & 63;
    const int quad = lane >> 4;
    const int l16  = lane & 15;
    const int m0   = blockIdx.x * BM;
    const int n0   = blockIdx.y * BN;
    const int wm   = (wave & 1) * 64;
    const int wn   = (wave >> 1) * 64;

    __shared__ short8 As[8 * (BM + 2)];
    __shared__ short8 Bs[8 * (BN + 2)];

    floatx4 acc[4][4];
#pragma unroll
    for (int i = 0; i < 4; i++)
#pragma unroll
        for (int j = 0; j < 4; j++) acc[i][j] = (floatx4){0.f, 0.f, 0.f, 0.f};

    for (int kt = 0; kt < K; kt += BK) {
        const unsigned short* Ap = (kt < 256) ? A0 : (kt < 512) ? A1 : A2;
        const int ko = kt & 255;
#pragma unroll
        for (int c = 0; c < 4; c++) {
            int lin = c * 256 + tid;
            int row = lin >> 3, kq = lin & 7;
            int gr = m0 + row; if (gr > M - 1) gr = M - 1;
            As[kq * (BM + 2) + row] = *(const short8*)(Ap + (size_t)gr * lda + ko + kq * 8);
        }
#pragma unroll
        for (int c = 0; c < 4; c++) {
            int lin = c * 256 + tid;
            int n = lin >> 3, kq = lin & 7;
            Bs[kq * (BN + 2) + n] = *(const short8*)(Bt + (size_t)(n0 + n) * ldb + kt + kq * 8);
        }
        __syncthreads();
#pragma unroll
        for (int s = 0; s < 2; s++) {
            short8 af[4], bfr[4];
#pragma unroll
            for (int i = 0; i < 4; i++)
                af[i] = As[(s * 4 + quad) * (BM + 2) + wm + i * 16 + l16];
#pragma unroll
            for (int j = 0; j < 4; j++)
                bfr[j] = Bs[(s * 4 + quad) * (BN + 2) + wn + j * 16 + l16];
#pragma unroll
            for (int i = 0; i < 4; i++)
#pragma unroll
                for (int j = 0; j < 4; j++)
                    acc[i][j] = __builtin_amdgcn_mfma_f32_16x16x32_bf16(
                        af[i], bfr[j], acc[i][j], 0, 0, 0);
        }
        __syncthreads();
    }

#pragma unroll
    for (int j = 0; j < 4; j++) {
        int gc = n0 + wn + j * 16 + l16;
        float bv = bias ? bf2f(bias[gc]) : 0.f;
#pragma unroll
        for (int i = 0; i < 4; i++) {
            int grb = m0 + wm + i * 16 + quad * 4;
#pragma unroll
            for (int r = 0; r < 4; r++) {
                int gr = grb + r;
                if (gr < M) {
                    float v = acc[i][j][r] + bv;
                    if (act) v = v > 0.f ? v : 0.01f * v;
                    C[(size_t)gr * ldc + gc] = f2bf(v);
                }
            }
        }
    }
}

// ---------- fused weight prep (all fp32 -> bf16) ----------
__global__ void k_prep(const float* __restrict__ Wd, const float* __restrict__ Wt,
                       const float* __restrict__ Wi, const float* __restrict__ Wo1,
                       const float* __restrict__ root1, const float* __restrict__ rel1,
                       const float* __restrict__ root2, const float* __restrict__ rel2,
                       const float* __restrict__ bd, const float* __restrict__ bt,
                       const float* __restrict__ bi, const float* __restrict__ b1,
                       const float* __restrict__ b2, const float* __restrict__ bo1,
                       unsigned short* __restrict__ WdT, unsigned short* __restrict__ WtT,
                       unsigned short* __restrict__ WiT, unsigned short* __restrict__ Wo1T,
                       unsigned short* __restrict__ BT1, unsigned short* __restrict__ BT2,
                       unsigned short* __restrict__ bias_bf)
{
    int i = blockIdx.x * 256 + threadIdx.x;
    if (i < 49152) { int r = i >> 6, c = i & 63; WdT[c * 768 + r] = f2bf(Wd[i]); return; }
    i -= 49152;
    if (i < 49152) { int r = i >> 6, c = i & 63; WtT[c * 768 + r] = f2bf(Wt[i]); return; }
    i -= 49152;
    if (i < 65536) { int r = i >> 8, c = i & 255; WiT[c * 256 + r] = f2bf(Wi[i]); return; }
    i -= 65536;
    if (i < 65536) { int r = i >> 8, c = i & 255; Wo1T[c * 256 + r] = f2bf(Wo1[i]); return; }
    i -= 65536;
    if (i < 196608) {
        int k = i % 768, n = i / 768;
        BT1[i] = f2bf(k < 256 ? root1[k * 256 + n] : rel1[(k - 256) * 256 + n]);
        return;
    }
    i -= 196608;
    if (i < 196608) {
        int k = i % 768, n = i / 768;
        BT2[i] = f2bf(k < 256 ? root2[k * 256 + n] : rel2[(k - 256) * 256 + n]);
        return;
    }
    i -= 196608;
    if (i < 1152) {
        const float* p; int off;
        if (i < 64)       { p = bd;  off = i; }
        else if (i < 128) { p = bt;  off = i - 64; }
        else if (i < 384) { p = bi;  off = i - 128; }
        else if (i < 640) { p = b1;  off = i - 384; }
        else if (i < 896) { p = b2;  off = i - 640; }
        else              { p = bo1; off = i - 896; }
        bias_bf[i] = f2bf(p[off]);
    }
}

// ---------- CSR build ----------
__global__ void k_hist(const int* __restrict__ ei, const int* __restrict__ et,
                       int* cnt2, int N, int E) {
    int e = blockIdx.x * 256 + threadIdx.x;
    if (e < E) {
        int dst = ei[E + e];
        int t = et[e] & 1;
        if ((unsigned)dst < (unsigned)N) atomicAdd(&cnt2[t * N + dst], 1);
    }
}

__global__ void k_scan1(const int* __restrict__ cnt2, int* rowptr, int* bsum, int N) {
    __shared__ int sh[256];
    int t = threadIdx.x;
    int base = blockIdx.x * 1024 + t * 4;
    int v[4];
    int s = 0;
#pragma unroll
    for (int k = 0; k < 4; k++) {
        int idx = base + k;
        v[k] = (idx < N) ? (cnt2[idx] + cnt2[N + idx]) : 0;
        s += v[k];
    }
    sh[t] = s;
    __syncthreads();
    for (int off = 1; off < 256; off <<= 1) {
        int x = 0;
        if (t >= off) x = sh[t - off];
        __syncthreads();
        if (t >= off) sh[t] += x;
        __syncthreads();
    }
    int excl = sh[t] - s;
    int run = excl;
#pragma unroll
    for (int k = 0; k < 4; k++) {
        int idx = base + k;
        if (idx < N) rowptr[idx] = run;
        run += v[k];
    }
    if (t == 255) bsum[blockIdx.x] = sh[255];
}

__global__ void k_scan2(const int* __restrict__ bsum, int* bofs, int nb) {
    int t = threadIdx.x;  // 64
    int v = (t < nb) ? bsum[t] : 0;
    int orig = v;
    for (int off = 1; off < 64; off <<= 1) {
        int x = __shfl_up(v, off);
        if (t >= off) v += x;
    }
    if (t < nb) bofs[t] = v - orig;
}

__global__ void k_scan3(int* rowptr, const int* __restrict__ bofs, int N) {
    int i = blockIdx.x * 256 + threadIdx.x;
    if (i < N) rowptr[i] += bofs[i >> 10];
}

__global__ void k_fill(const int* __restrict__ ei, const int* __restrict__ et,
                       const int* __restrict__ rowptr, int* cursor, int* sorted,
                       int N, int E) {
    int e = blockIdx.x * 256 + threadIdx.x;
    if (e < E) {
        int src = ei[e];
        int dst = ei[E + e];
        int t = et[e] & 1;
        if ((unsigned)dst < (unsigned)N && (unsigned)src < (unsigned)N) {
            int pos = rowptr[dst] + atomicAdd(&cursor[dst], 1);
            sorted[pos] = src | (t << 24);
        }
    }
}

// ---------- aggregation: one wave per node, 2 edges/iter, 4 loads in flight ----------
__global__ __launch_bounds__(256) void k_agg(
    const unsigned short* __restrict__ x,
    unsigned short* __restrict__ m0,
    unsigned short* __restrict__ m1,
    int N,
    const int* __restrict__ rowptr, const int* __restrict__ cnt2,
    const int* __restrict__ sorted)
{
    int wave = threadIdx.x >> 6;
    int lane = threadIdx.x & 63;
    int half = lane >> 5;
    int l32  = lane & 31;
    int node = blockIdx.x * 4 + wave;
    if (node >= N) return;

    int start = rowptr[node];
    int c0 = cnt2[node], c1 = cnt2[N + node];
    int deg = c0 + c1;

    float a0[8] = {0,0,0,0,0,0,0,0};
    float a1[8] = {0,0,0,0,0,0,0,0};

    for (int b = 0; b < deg; b += 64) {
        int rem = deg - b; if (rem > 64) rem = 64;
        int p = 0;
        if (lane < rem) p = sorted[start + b + lane];
        int iters = (rem + 1) >> 1;
        for (int t = 0; t < iters; t += 2) {
            int e0 = 2 * t + half;
            int e1 = e0 + 2;
            int q0 = __shfl(p, e0 < 64 ? e0 : 63);
            int q1 = __shfl(p, e1 < 64 ? e1 : 63);
            bool v0ok = e0 < rem;
            bool v1ok = e1 < rem;
            int s0 = q0 & 0xFFFFFF; if (s0 >= N) s0 = 0;
            int s1 = q1 & 0xFFFFFF; if (s1 >= N) s1 = 0;
            uint4 r0 = *((const uint4*)(x + (size_t)s0 * 256) + l32);
            uint4 r1 = *((const uint4*)(x + (size_t)s1 * 256) + l32);
            if (v0ok) {
                float f[8];
                f[0] = bf2f((unsigned short)(r0.x & 0xFFFFu)); f[1] = bf2f((unsigned short)(r0.x >> 16));
                f[2] = bf2f((unsigned short)(r0.y & 0xFFFFu)); f[3] = bf2f((unsigned short)(r0.y >> 16));
                f[4] = bf2f((unsigned short)(r0.z & 0xFFFFu)); f[5] = bf2f((unsigned short)(r0.z >> 16));
                f[6] = bf2f((unsigned short)(r0.w & 0xFFFFu)); f[7] = bf2f((unsigned short)(r0.w >> 16));
                if ((q0 >> 24) & 1) {
#pragma unroll
                    for (int k = 0; k < 8; k++) a1[k] += f[k];
                } else {
#pragma unroll
                    for (int k = 0; k < 8; k++) a0[k] += f[k];
                }
            }
            if (v1ok) {
                float f[8];
                f[0] = bf2f((unsigned short)(r1.x & 0xFFFFu)); f[1] = bf2f((unsigned short)(r1.x >> 16));
                f[2] = bf2f((unsigned short)(r1.y & 0xFFFFu)); f[3] = bf2f((unsigned short)(r1.y >> 16));
                f[4] = bf2f((unsigned short)(r1.z & 0xFFFFu)); f[5] = bf2f((unsigned short)(r1.z >> 16));
                f[6] = bf2f((unsigned short)(r1.w & 0xFFFFu)); f[7] = bf2f((unsigned short)(r1.w >> 16));
                if ((q1 >> 24) & 1) {
#pragma unroll
                    for (int k = 0; k < 8; k++) a1[k] += f[k];
                } else {
#pragma unroll
                    for (int k = 0; k < 8; k++) a0[k] += f[k];
                }
            }
        }
    }
#pragma unroll
    for (int k = 0; k < 8; k++) {
        a0[k] += __shfl_xor(a0[k], 32);
        a1[k] += __shfl_xor(a1[k], 32);
    }
    float i0 = c0 > 0 ? 1.f / (float)c0 : 0.f;
    float i1 = c1 > 0 ? 1.f / (float)c1 : 0.f;
    uint4 o;
    if (half == 0) {
        o.x = (unsigned)f2bf(a0[0] * i0) | ((unsigned)f2bf(a0[1] * i0) << 16);
        o.y = (unsigned)f2bf(a0[2] * i0) | ((unsigned)f2bf(a0[3] * i0) << 16);
        o.z = (unsigned)f2bf(a0[4] * i0) | ((unsigned)f2bf(a0[5] * i0) << 16);
        o.w = (unsigned)f2bf(a0[6] * i0) | ((unsigned)f2bf(a0[7] * i0) << 16);
        *((uint4*)(m0 + (size_t)node * 256) + l32) = o;
    } else {
        o.x = (unsigned)f2bf(a1[0] * i1) | ((unsigned)f2bf(a1[1] * i1) << 16);
        o.y = (unsigned)f2bf(a1[2] * i1) | ((unsigned)f2bf(a1[3] * i1) << 16);
        o.z = (unsigned)f2bf(a1[4] * i1) | ((unsigned)f2bf(a1[5] * i1) << 16);
        o.w = (unsigned)f2bf(a1[6] * i1) | ((unsigned)f2bf(a1[7] * i1) << 16);
        *((uint4*)(m1 + (size_t)node * 256) + l32) = o;
    }
}

// ---------- small-K encode (num K=5 -> cols 128..191, cat K=3 -> 192..255) ----------
__global__ void k_small(const float* __restrict__ num, const float* __restrict__ cat,
                        const float* __restrict__ Wn, const float* __restrict__ bnp,
                        const float* __restrict__ Wc, const float* __restrict__ bcp,
                        unsigned short* __restrict__ xcat, int N)
{
    __shared__ float wn[320], wc[192], bns[64], bcs[64];
    int t = threadIdx.x;
    for (int i = t; i < 320; i += 256) wn[i] = Wn[i];
    for (int i = t; i < 192; i += 256) wc[i] = Wc[i];
    if (t < 64) { bns[t] = bnp[t]; bcs[t] = bcp[t]; }
    __syncthreads();

    int node = blockIdx.x * 128 + (t >> 1);
    int half = t & 1;
    if (node >= N) return;
    if (half == 0) {
        float in5[5];
#pragma unroll
        for (int i = 0; i < 5; i++) in5[i] = num[(size_t)node * 5 + i];
        unsigned short* orow = xcat + (size_t)node * 256 + 128;
#pragma unroll 4
        for (int c = 0; c < 64; c++) {
            float v = bns[c];
#pragma unroll
            for (int i = 0; i < 5; i++) v += in5[i] * wn[i * 64 + c];
            v = v > 0.f ? v : 0.01f * v;
            orow[c] = f2bf(v);
        }
    } else {
        float in3[3];
#pragma unroll
        for (int i = 0; i < 3; i++) in3[i] = cat[(size_t)node * 3 + i];
        unsigned short* orow = xcat + (size_t)node * 256 + 192;
#pragma unroll 4
        for (int c = 0; c < 64; c++) {
            float v = bcs[c];
#pragma unroll
            for (int i = 0; i < 3; i++) v += in3[i] * wc[i * 64 + c];
            v = v > 0.f ? v : 0.01f * v;
            orow[c] = f2bf(v);
        }
    }
}

// ---------- final projection: out[N,2](fp32) = z[N,256] @ Wo2[256,2] + bo2 ----------
__global__ __launch_bounds__(256) void k_final(
    const unsigned short* __restrict__ z,
    const float* __restrict__ Wo2, const float* __restrict__ bo2,
    float* __restrict__ out, int N)
{
    __shared__ float w[512];
    int t = threadIdx.x;
    for (int i = t; i < 512; i += 256) w[i] = Wo2[i];
    __syncthreads();
    int wave = t >> 6, lane = t & 63;
    int node = blockIdx.x * 4 + wave;
    if (node >= N) return;
    uint2 raw = *((const uint2*)(z + (size_t)node * 256) + lane);
    float v0 = bf2f((unsigned short)(raw.x & 0xFFFFu));
    float v1 = bf2f((unsigned short)(raw.x >> 16));
    float v2 = bf2f((unsigned short)(raw.y & 0xFFFFu));
    float v3 = bf2f((unsigned short)(raw.y >> 16));
    int k0 = lane * 4;
    float s0 = v0 * w[k0 * 2]     + v1 * w[(k0 + 1) * 2]     + v2 * w[(k0 + 2) * 2]     + v3 * w[(k0 + 3) * 2];
    float s1 = v0 * w[k0 * 2 + 1] + v1 * w[(k0 + 1) * 2 + 1] + v2 * w[(k0 + 2) * 2 + 1] + v3 * w[(k0 + 3) * 2 + 1];
    for (int off = 32; off; off >>= 1) {
        s0 += __shfl_xor(s0, off);
        s1 += __shfl_xor(s1, off);
    }
    if (lane == 0) {
        out[(size_t)node * 2]     = s0 + bo2[0];
        out[(size_t)node * 2 + 1] = s1 + bo2[1];
    }
}

// ---------------------------------------------------------------------------
extern "C" void kernel_launch(void* const* d_in, const int* in_sizes, int n_in,
                              void* d_out, int out_size, void* d_ws, size_t ws_size,
                              hipStream_t stream)
{
    (void)n_in; (void)out_size; (void)ws_size;
    const float* des   = (const float*)d_in[0];
    const float* tweet = (const float*)d_in[1];
    const float* nump  = (const float*)d_in[2];
    const float* catp  = (const float*)d_in[3];
    const int*   ei    = (const int*)d_in[4];
    const int*   et    = (const int*)d_in[5];
    const float* Wd  = (const float*)d_in[6];
    const float* bd  = (const float*)d_in[7];
    const float* Wt  = (const float*)d_in[8];
    const float* bt  = (const float*)d_in[9];
    const float* Wn  = (const float*)d_in[10];
    const float* bn  = (const float*)d_in[11];
    const float* Wc  = (const float*)d_in[12];
    const float* bc  = (const float*)d_in[13];
    const float* Wi  = (const float*)d_in[14];
    const float* bi  = (const float*)d_in[15];
    const float* rel1  = (const float*)d_in[16];
    const float* root1 = (const float*)d_in[17];
    const float* bias1 = (const float*)d_in[18];
    const float* rel2  = (const float*)d_in[19];
    const float* root2 = (const float*)d_in[20];
    const float* bias2 = (const float*)d_in[21];
    const float* Wo1 = (const float*)d_in[22];
    const float* bo1 = (const float*)d_in[23];
    const float* Wo2 = (const float*)d_in[24];
    const float* bo2 = (const float*)d_in[25];

    const int N = in_sizes[0] / 768;
    const int E = in_sizes[5];

    char* ws = (char*)d_ws;
    size_t off = 0;
    auto alloc = [&](size_t bytes) -> char* {
        char* p = ws + off;
        off += (bytes + 255) & ~(size_t)255;
        return p;
    };
    unsigned short* B0 = (unsigned short*)alloc((size_t)N * 256 * 2);  // xcat / y1 / z
    unsigned short* B1 = (unsigned short*)alloc((size_t)N * 256 * 2);  // x / y2
    unsigned short* B2 = (unsigned short*)alloc((size_t)N * 256 * 2);  // m0
    unsigned short* B3 = (unsigned short*)alloc((size_t)N * 256 * 2);  // m1
    unsigned short* WdT  = (unsigned short*)alloc(64 * 768 * 2);
    unsigned short* WtT  = (unsigned short*)alloc(64 * 768 * 2);
    unsigned short* WiT  = (unsigned short*)alloc(256 * 256 * 2);
    unsigned short* Wo1T = (unsigned short*)alloc(256 * 256 * 2);
    unsigned short* BT1  = (unsigned short*)alloc(256 * 768 * 2);
    unsigned short* BT2  = (unsigned short*)alloc(256 * 768 * 2);
    unsigned short* bias_bf = (unsigned short*)alloc(1152 * 2);
    unsigned short* bd_bf = bias_bf;          // 64
    unsigned short* bi_bf = bias_bf + 128;    // 256
    unsigned short* b1_bf = bias_bf + 384;    // 256
    unsigned short* b2_bf = bias_bf + 640;    // 256
    unsigned short* bo1_bf = bias_bf + 896;   // 256
    int* cnt2   = (int*)alloc((size_t)2 * N * 4);   // adjacent to cursor
    int* cursor = (int*)alloc((size_t)N * 4);
    int* rowptr = (int*)alloc((size_t)(N + 1) * 4);
    int* bsum   = (int*)alloc(64 * 4);
    int* bofs   = (int*)alloc(64 * 4);
    int* sorted = (int*)alloc((size_t)E * 4);

    // zero cnt2 + cursor
    size_t zlen = (size_t)(((char*)cursor + (size_t)N * 4) - (char*)cnt2);
    hipMemsetAsync(cnt2, 0, zlen, stream);

    // fused weight prep: 623744 elements
    k_prep<<<(623744 + 255) / 256, 256, 0, stream>>>(
        Wd, Wt, Wi, Wo1, root1, rel1, root2, rel2,
        bd, bt, bi, bias1, bias2, bo1,
        WdT, WtT, WiT, Wo1T, BT1, BT2, bias_bf);

    // CSR build
    int eb = (E + 255) / 256;
    k_hist<<<eb, 256, 0, stream>>>(ei, et, cnt2, N, E);
    int nb = (N + 1023) / 1024;
    k_scan1<<<nb, 256, 0, stream>>>(cnt2, rowptr, bsum, N);
    k_scan2<<<1, 64, 0, stream>>>(bsum, bofs, nb);
    k_scan3<<<(N + 255) / 256, 256, 0, stream>>>(rowptr, bofs, N);
    k_fill<<<eb, 256, 0, stream>>>(ei, et, rowptr, cursor, sorted, N, E);

    // streaming feature encode -> B0 cols 0..127 (des 0..63, tweet 64..127)
    dim3 gEnc((N + 63) / 64, 2);
    k_encode<<<gEnc, 256, 0, stream>>>(des, tweet, WdT, WtT, bd_bf, B0, N);
    k_small<<<(N + 127) / 128, 256, 0, stream>>>(nump, catp, Wn, bn, Wc, bc, B0, N);

    // x = lrelu(xcat @ Wi + bi) -> B1
    dim3 g128((N + 127) / 128, 2);
    gemm_nt<<<g128, 256, 0, stream>>>(B0, B0, B0, 256, WiT, 256, B1, 256, bi_bf, N, 256, 1);

    // RGCN layer 1: aggregate x (B1) -> B2, B3; fused K=768 GEMM -> B0
    int ab = (N + 3) / 4;
    k_agg<<<ab, 256, 0, stream>>>(B1, B2, B3, N, rowptr, cnt2, sorted);
    gemm_nt<<<g128, 256, 0, stream>>>(B1, B2, B3, 256, BT1, 768, B0, 256, b1_bf, N, 768, 0);

    // RGCN layer 2: aggregate y1 (B0) -> B2, B3; GEMM -> B1
    k_agg<<<ab, 256, 0, stream>>>(B0, B2, B3, N, rowptr, cnt2, sorted);
    gemm_nt<<<g128, 256, 0, stream>>>(B0, B2, B3, 256, BT2, 768, B1, 256, b2_bf, N, 768, 0);

    // z = lrelu(y2 @ Wo1 + bo1) -> B0
    gemm_nt<<<g128, 256, 0, stream>>>(B1, B1, B1, 256, Wo1T, 256, B0, 256, bo1_bf, N, 256, 1);

    // out = z @ Wo2 + bo2 (fp32)
    k_final<<<ab, 256, 0, stream>>>(B0, Wo2, bo2, (float*)d_out, N);
}